// Round 1
// baseline (654.475 us; speedup 1.0000x reference)
//
#include <hip/hip_runtime.h>

#define N_NODES 20000
#define N_EDGES 640000
#define E_TOT   (N_EDGES + N_NODES)   /* 660000: edges + self loops */
#define IN_DIM  128
#define HIDDEN  256
#define OUT_DIM 64

// ---------------- CSR build (by dst) ----------------

__global__ void zero_cnt_kernel(int* __restrict__ cnt) {
    int i = blockIdx.x * blockDim.x + threadIdx.x;
    if (i < N_NODES) cnt[i] = 0;
}

__global__ void count_kernel(const int* __restrict__ edge_dst, int* __restrict__ cnt) {
    int i = blockIdx.x * blockDim.x + threadIdx.x;
    if (i >= E_TOT) return;
    int d = (i < N_EDGES) ? edge_dst[i] : (i - N_EDGES);   // implicit self-loop tail
    atomicAdd(&cnt[d], 1);
}

// Single-block exclusive scan over 20000 counts -> indptr[20001]; also re-zeros cnt
// for reuse as the scatter cursor.
__global__ __launch_bounds__(1024) void scan_kernel(int* __restrict__ cnt, int* __restrict__ indptr) {
    const int T = 1024;
    const int C = (N_NODES + T - 1) / T;   // 20 per thread
    __shared__ int sums[T];
    int t = threadIdx.x;
    int base = t * C;
    int local[C];
    int s = 0;
#pragma unroll
    for (int i = 0; i < C; i++) {
        int idx = base + i;
        int v = (idx < N_NODES) ? cnt[idx] : 0;
        local[i] = s;
        s += v;
    }
    sums[t] = s;
    __syncthreads();
    // Hillis-Steele inclusive scan of per-thread sums
    for (int off = 1; off < T; off <<= 1) {
        int v = (t >= off) ? sums[t - off] : 0;
        __syncthreads();
        sums[t] += v;
        __syncthreads();
    }
    int prefix = (t == 0) ? 0 : sums[t - 1];
#pragma unroll
    for (int i = 0; i < C; i++) {
        int idx = base + i;
        if (idx < N_NODES) {
            indptr[idx] = prefix + local[i];
            cnt[idx] = 0;                   // cursor for scatter
        }
    }
    if (t == T - 1) indptr[N_NODES] = prefix + s;   // == E_TOT
}

__global__ void scatter_kernel(const int* __restrict__ edge_src, const int* __restrict__ edge_dst,
                               const int* __restrict__ indptr, int* __restrict__ cnt,
                               int* __restrict__ ssrc) {
    int i = blockIdx.x * blockDim.x + threadIdx.x;
    if (i >= E_TOT) return;
    int d, s;
    if (i < N_EDGES) { d = edge_dst[i]; s = edge_src[i]; }
    else             { d = i - N_EDGES; s = d; }
    int pos = indptr[d] + atomicAdd(&cnt[d], 1);
    ssrc[pos] = s;
}

// ---------------- fp32 tiled GEMM + bias + optional relu ----------------
// C[M,Nn] = act(A[M,K] @ B[K,Nn] + bias[Nn]); BM=BN=64, BK=16, 256 thr, 4x4/thread.

__global__ __launch_bounds__(256) void gemm_bias_act(const float* __restrict__ A,
                                                     const float* __restrict__ B,
                                                     const float* __restrict__ bias,
                                                     float* __restrict__ C,
                                                     int M, int Nn, int K, int relu) {
    __shared__ float As[16][65];
    __shared__ float Bs[16][65];
    int tid = threadIdx.x;
    int tx = tid & 15, ty = tid >> 4;
    int row0 = blockIdx.x * 64, col0 = blockIdx.y * 64;
    float acc[4][4] = {};
    for (int k0 = 0; k0 < K; k0 += 16) {
        {   // A tile: 64 rows x 16 k, float4 per thread
            int r_ = tid >> 2;
            int kq = (tid & 3) * 4;
            int gr = row0 + r_;
            float4 a4 = make_float4(0.f, 0.f, 0.f, 0.f);
            if (gr < M) a4 = *(const float4*)&A[(long)gr * K + k0 + kq];
            As[kq + 0][r_] = a4.x; As[kq + 1][r_] = a4.y;
            As[kq + 2][r_] = a4.z; As[kq + 3][r_] = a4.w;
        }
        {   // B tile: 16 k x 64 cols, float4 per thread
            int kr = tid >> 4;
            int cq = (tid & 15) * 4;
            float4 b4 = *(const float4*)&B[(long)(k0 + kr) * Nn + col0 + cq];
            Bs[kr][cq + 0] = b4.x; Bs[kr][cq + 1] = b4.y;
            Bs[kr][cq + 2] = b4.z; Bs[kr][cq + 3] = b4.w;
        }
        __syncthreads();
#pragma unroll
        for (int kk = 0; kk < 16; kk++) {
            float a[4], b[4];
#pragma unroll
            for (int i = 0; i < 4; i++) a[i] = As[kk][ty * 4 + i];
#pragma unroll
            for (int j = 0; j < 4; j++) b[j] = Bs[kk][tx * 4 + j];
#pragma unroll
            for (int i = 0; i < 4; i++)
#pragma unroll
                for (int j = 0; j < 4; j++) acc[i][j] += a[i] * b[j];
        }
        __syncthreads();
    }
#pragma unroll
    for (int i = 0; i < 4; i++) {
        int gr = row0 + ty * 4 + i;
        if (gr >= M) continue;
#pragma unroll
        for (int j = 0; j < 4; j++) {
            int gc = col0 + tx * 4 + j;
            float v = acc[i][j] + bias[gc];
            if (relu) v = fmaxf(v, 0.f);
            C[(long)gr * Nn + gc] = v;
        }
    }
}

// ---------------- row L2-normalize: hn = h * rsqrt(sum h^2 + eps), r = ||h|| ----------------

__global__ __launch_bounds__(256) void normalize_kernel(const float* __restrict__ h,
                                                        float* __restrict__ hn,
                                                        float* __restrict__ r) {
    int i = blockIdx.x;
    int c = threadIdx.x;
    float v = h[(long)i * HIDDEN + c];
    float ss = v * v;
#pragma unroll
    for (int off = 32; off; off >>= 1) ss += __shfl_xor(ss, off);
    __shared__ float wsum[4];
    int wid = c >> 6, lane = c & 63;
    if (lane == 0) wsum[wid] = ss;
    __syncthreads();
    float tot = wsum[0] + wsum[1] + wsum[2] + wsum[3];
    float rr = sqrtf(tot + 1e-12f);
    hn[(long)i * HIDDEN + c] = v / rr;
    if (c == 0) r[i] = rr;
}

// ---------------- fused AGNN layer: one wave per dst node, online softmax ----------------
// out[i] = relu( sum_e softmax(cos(hn_i, hn_src)) * (r_src * hn_src) )

__global__ __launch_bounds__(256) void agnn_kernel(const float* __restrict__ hn,
                                                   const float* __restrict__ r,
                                                   const int* __restrict__ indptr,
                                                   const int* __restrict__ ssrc,
                                                   float* __restrict__ hout) {
    int wid = threadIdx.x >> 6;
    int lane = threadIdx.x & 63;
    int node = blockIdx.x * 4 + wid;
    if (node >= N_NODES) return;

    const float4* hn4 = (const float4*)hn;
    float4 hd = hn4[(long)node * 64 + lane];   // this dst's normalized row (4 ch/lane)

    int beg = indptr[node], end = indptr[node + 1];   // deg >= 1 (self loop)
    float m = -INFINITY, z = 0.f;
    float4 acc = make_float4(0.f, 0.f, 0.f, 0.f);

    // 2-stage pipeline: prefetch next edge's row while reducing current
    int s0 = ssrc[beg];
    float4 v = hn4[(long)s0 * 64 + lane];
    float rs = r[s0];

    for (int e = beg; e < end; e++) {
        float4 cv = v;
        float crs = rs;
        if (e + 1 < end) {
            int sn = ssrc[e + 1];
            v = hn4[(long)sn * 64 + lane];
            rs = r[sn];
        }
        float d = hd.x * cv.x + hd.y * cv.y + hd.z * cv.z + hd.w * cv.w;
#pragma unroll
        for (int off = 32; off; off >>= 1) d += __shfl_xor(d, off);
        float nm = fmaxf(m, d);
        float sc = expf(m - nm);      // expf(-inf)=0 on first edge
        float w = expf(d - nm);
        z = z * sc + w;
        float wr = w * crs;
        acc.x = acc.x * sc + wr * cv.x;
        acc.y = acc.y * sc + wr * cv.y;
        acc.z = acc.z * sc + wr * cv.z;
        acc.w = acc.w * sc + wr * cv.w;
        m = nm;
    }
    float inv = 1.f / z;
    float4 o;
    o.x = fmaxf(acc.x * inv, 0.f);
    o.y = fmaxf(acc.y * inv, 0.f);
    o.z = fmaxf(acc.z * inv, 0.f);
    o.w = fmaxf(acc.w * inv, 0.f);
    ((float4*)hout)[(long)node * 64 + lane] = o;
}

// ---------------- launch ----------------

extern "C" void kernel_launch(void* const* d_in, const int* in_sizes, int n_in,
                              void* d_out, int out_size, void* d_ws, size_t ws_size,
                              hipStream_t stream) {
    const float* x  = (const float*)d_in[0];
    const int* esrc = (const int*)d_in[1];
    const int* edst = (const int*)d_in[2];
    const float* W1 = (const float*)d_in[3];
    const float* b1 = (const float*)d_in[4];
    const float* W2 = (const float*)d_in[5];
    const float* b2 = (const float*)d_in[6];
    float* out = (float*)d_out;

    char* ws = (char*)d_ws;
    // layout (bytes): h0[20.48M] h1[20.48M] hn[20.48M] r[80K] indptr cnt ssrc
    float* h0     = (float*)(ws);
    float* h1     = (float*)(ws + 20480000);
    float* hn     = (float*)(ws + 40960000);
    float* rb     = (float*)(ws + 61440000);
    int*   indptr = (int*)  (ws + 61520000);
    int*   cnt    = (int*)  (ws + 61600256);
    int*   ssrc   = (int*)  (ws + 61680256);

    zero_cnt_kernel<<<(N_NODES + 255) / 256, 256, 0, stream>>>(cnt);
    count_kernel<<<(E_TOT + 255) / 256, 256, 0, stream>>>(edst, cnt);
    scan_kernel<<<1, 1024, 0, stream>>>(cnt, indptr);
    scatter_kernel<<<(E_TOT + 255) / 256, 256, 0, stream>>>(esrc, edst, indptr, cnt, ssrc);

    dim3 g1((N_NODES + 63) / 64, HIDDEN / 64);
    gemm_bias_act<<<g1, 256, 0, stream>>>(x, W1, b1, h0, N_NODES, HIDDEN, IN_DIM, 1);

    float* ha = h0;
    float* hb = h1;
    for (int l = 0; l < 4; l++) {
        normalize_kernel<<<N_NODES, 256, 0, stream>>>(ha, hn, rb);
        agnn_kernel<<<(N_NODES + 3) / 4, 256, 0, stream>>>(hn, rb, indptr, ssrc, hb);
        float* t = ha; ha = hb; hb = t;
    }

    dim3 g2((N_NODES + 63) / 64, OUT_DIM / 64);
    gemm_bias_act<<<g2, 256, 0, stream>>>(ha, W2, b2, out, N_NODES, OUT_DIM, HIDDEN, 0);
}

// Round 2
// 364.849 us; speedup vs baseline: 1.7938x; 1.7938x over previous
//
#include <hip/hip_runtime.h>

#define N_NODES 20000
#define N_EDGES 640000
#define E_TOT   (N_EDGES + N_NODES)   /* 660000: edges + self loops */
#define IN_DIM  128
#define HIDDEN  256
#define OUT_DIM 64
#define LOG2E 1.4426950408889634f

typedef __attribute__((ext_vector_type(8))) short short8;

__device__ __forceinline__ float bf2f(unsigned short u) {
    union { unsigned int i; float f; } x; x.i = ((unsigned int)u) << 16; return x.f;
}
__device__ __forceinline__ unsigned short f2bf(float f) {
    union { float f; unsigned int i; } x; x.f = f;
    unsigned int u = x.i;
    return (unsigned short)((u + 0x7fffu + ((u >> 16) & 1u)) >> 16);  // RTNE
}

// ---------------- CSR build (by dst) ----------------

__global__ void zero_cnt_kernel(int* __restrict__ cnt) {
    int i = blockIdx.x * blockDim.x + threadIdx.x;
    if (i < N_NODES) cnt[i] = 0;
}

__global__ void count_kernel(const int* __restrict__ edge_dst, int* __restrict__ cnt) {
    int i = blockIdx.x * blockDim.x + threadIdx.x;
    if (i >= E_TOT) return;
    int d = (i < N_EDGES) ? edge_dst[i] : (i - N_EDGES);   // implicit self-loop tail
    atomicAdd(&cnt[d], 1);
}

__global__ __launch_bounds__(1024) void scan_kernel(int* __restrict__ cnt, int* __restrict__ indptr) {
    const int T = 1024;
    const int C = (N_NODES + T - 1) / T;   // 20 per thread
    __shared__ int sums[T];
    int t = threadIdx.x;
    int base = t * C;
    int local[C];
    int s = 0;
#pragma unroll
    for (int i = 0; i < C; i++) {
        int idx = base + i;
        int v = (idx < N_NODES) ? cnt[idx] : 0;
        local[i] = s;
        s += v;
    }
    sums[t] = s;
    __syncthreads();
    for (int off = 1; off < T; off <<= 1) {
        int v = (t >= off) ? sums[t - off] : 0;
        __syncthreads();
        sums[t] += v;
        __syncthreads();
    }
    int prefix = (t == 0) ? 0 : sums[t - 1];
#pragma unroll
    for (int i = 0; i < C; i++) {
        int idx = base + i;
        if (idx < N_NODES) {
            indptr[idx] = prefix + local[i];
            cnt[idx] = 0;                   // cursor for scatter
        }
    }
    if (t == T - 1) indptr[N_NODES] = prefix + s;   // == E_TOT
}

__global__ void scatter_kernel(const int* __restrict__ edge_src, const int* __restrict__ edge_dst,
                               const int* __restrict__ indptr, int* __restrict__ cnt,
                               int* __restrict__ ssrc) {
    int i = blockIdx.x * blockDim.x + threadIdx.x;
    if (i >= E_TOT) return;
    int d, s;
    if (i < N_EDGES) { d = edge_dst[i]; s = edge_src[i]; }
    else             { d = i - N_EDGES; s = d; }
    int pos = indptr[d] + atomicAdd(&cnt[d], 1);
    ssrc[pos] = s;
}

// ---------------- fp32 tiled GEMM + bias + optional relu ----------------

__global__ __launch_bounds__(256) void gemm_bias_act(const float* __restrict__ A,
                                                     const float* __restrict__ B,
                                                     const float* __restrict__ bias,
                                                     float* __restrict__ C,
                                                     int M, int Nn, int K, int relu) {
    __shared__ float As[16][65];
    __shared__ float Bs[16][65];
    int tid = threadIdx.x;
    int tx = tid & 15, ty = tid >> 4;
    int row0 = blockIdx.x * 64, col0 = blockIdx.y * 64;
    float acc[4][4] = {};
    for (int k0 = 0; k0 < K; k0 += 16) {
        {
            int r_ = tid >> 2;
            int kq = (tid & 3) * 4;
            int gr = row0 + r_;
            float4 a4 = make_float4(0.f, 0.f, 0.f, 0.f);
            if (gr < M) a4 = *(const float4*)&A[(long)gr * K + k0 + kq];
            As[kq + 0][r_] = a4.x; As[kq + 1][r_] = a4.y;
            As[kq + 2][r_] = a4.z; As[kq + 3][r_] = a4.w;
        }
        {
            int kr = tid >> 4;
            int cq = (tid & 15) * 4;
            float4 b4 = *(const float4*)&B[(long)(k0 + kr) * Nn + col0 + cq];
            Bs[kr][cq + 0] = b4.x; Bs[kr][cq + 1] = b4.y;
            Bs[kr][cq + 2] = b4.z; Bs[kr][cq + 3] = b4.w;
        }
        __syncthreads();
#pragma unroll
        for (int kk = 0; kk < 16; kk++) {
            float a[4], b[4];
#pragma unroll
            for (int i = 0; i < 4; i++) a[i] = As[kk][ty * 4 + i];
#pragma unroll
            for (int j = 0; j < 4; j++) b[j] = Bs[kk][tx * 4 + j];
#pragma unroll
            for (int i = 0; i < 4; i++)
#pragma unroll
                for (int j = 0; j < 4; j++) acc[i][j] += a[i] * b[j];
        }
        __syncthreads();
    }
#pragma unroll
    for (int i = 0; i < 4; i++) {
        int gr = row0 + ty * 4 + i;
        if (gr >= M) continue;
#pragma unroll
        for (int j = 0; j < 4; j++) {
            int gc = col0 + tx * 4 + j;
            float v = acc[i][j] + bias[gc];
            if (relu) v = fmaxf(v, 0.f);
            C[(long)gr * Nn + gc] = v;
        }
    }
}

// ---------------- initial normalize: fp32 h -> bf16 hn + fp32 r ----------------

__global__ __launch_bounds__(256) void normalize0_kernel(const float* __restrict__ h,
                                                         unsigned short* __restrict__ hnb,
                                                         float* __restrict__ r) {
    int i = blockIdx.x;
    int c = threadIdx.x;
    float v = h[(long)i * HIDDEN + c];
    float ss = v * v;
#pragma unroll
    for (int off = 32; off; off >>= 1) ss += __shfl_xor(ss, off);
    __shared__ float wsum[4];
    int wid = c >> 6, lane = c & 63;
    if (lane == 0) wsum[wid] = ss;
    __syncthreads();
    float tot = wsum[0] + wsum[1] + wsum[2] + wsum[3];
    float rr = sqrtf(tot + 1e-12f);
    hnb[(long)i * HIDDEN + c] = f2bf(v / rr);
    if (c == 0) r[i] = rr;
}

// ---------------- fused AGNN layer ----------------
// One wave per dst node; two half-waves each stream half the edge list with an
// independent online-softmax state (8 ch/lane), merged at the end via shfl(32).
// Epilogue optionally re-normalizes and emits bf16 hn + r for the next layer.

__global__ __launch_bounds__(256) void agnn_kernel(const unsigned short* __restrict__ hnb,
                                                   const float* __restrict__ rin,
                                                   const int* __restrict__ indptr,
                                                   const int* __restrict__ ssrc,
                                                   unsigned short* __restrict__ hnout,
                                                   float* __restrict__ rout,
                                                   float* __restrict__ hout,
                                                   int write_hn) {
    int wid = threadIdx.x >> 6;
    int lane = threadIdx.x & 63;
    int node = blockIdx.x * 4 + wid;
    if (node >= N_NODES) return;
    int l32 = lane & 31;
    int halfid = lane >> 5;

    const short8* tab = (const short8*)hnb;
    short8 hdv = tab[(long)node * 32 + l32];
    float hd[8];
#pragma unroll
    for (int j = 0; j < 8; j++) hd[j] = bf2f((unsigned short)hdv[j]);

    int beg = indptr[node], end = indptr[node + 1];
    int deg = end - beg;                 // >= 1 (self loop)
    int cA = (deg + 1) >> 1;
    int cnt = halfid ? (deg - cA) : cA;
    int eb = beg + (halfid ? cA : 0);

    float m2 = -INFINITY, z = 0.f;
    float acc[8] = {0.f, 0.f, 0.f, 0.f, 0.f, 0.f, 0.f, 0.f};

    int s0 = (cnt > 0) ? ssrc[eb] : 0;
    short8 v = tab[(long)s0 * 32 + l32];
    float rs = rin[s0];

    for (int i = 0; i < cnt; i++) {
        short8 cv = v;
        float crs = rs;
        if (i + 1 < cnt) {
            int sn = ssrc[eb + i + 1];
            v = tab[(long)sn * 32 + l32];
            rs = rin[sn];
        }
        float cf[8];
        float dot = 0.f;
#pragma unroll
        for (int j = 0; j < 8; j++) { cf[j] = bf2f((unsigned short)cv[j]); dot += hd[j] * cf[j]; }
#pragma unroll
        for (int off = 16; off; off >>= 1) dot += __shfl_xor(dot, off);   // within 32-lane half
        float d2 = dot * LOG2E;
        if (d2 <= m2) {               // fast path: wave-half-uniform branch
            float w = exp2f(d2 - m2);
            z += w;
            float wr = w * crs;
#pragma unroll
            for (int j = 0; j < 8; j++) acc[j] += wr * cf[j];
        } else {                      // new max: rescale (exp2f(-inf)=0 on first edge)
            float sc = exp2f(m2 - d2);
            z = z * sc + 1.f;
#pragma unroll
            for (int j = 0; j < 8; j++) acc[j] = acc[j] * sc + crs * cf[j];
            m2 = d2;
        }
    }

    // merge the two half-wave softmax states (symmetric -> both halves get result)
    float om = __shfl_xor(m2, 32);
    float oz = __shfl_xor(z, 32);
    float oa[8];
#pragma unroll
    for (int j = 0; j < 8; j++) oa[j] = __shfl_xor(acc[j], 32);
    float nm = fmaxf(m2, om);
    float sA = exp2f(m2 - nm);
    float sB = exp2f(om - nm);
    z = z * sA + oz * sB;
    float inv = 1.f / z;
    float o[8];
#pragma unroll
    for (int j = 0; j < 8; j++) o[j] = fmaxf((acc[j] * sA + oa[j] * sB) * inv, 0.f);

    if (write_hn) {
        float ss = 0.f;
#pragma unroll
        for (int j = 0; j < 8; j++) ss += o[j] * o[j];
#pragma unroll
        for (int off = 16; off; off >>= 1) ss += __shfl_xor(ss, off);
        float rr = sqrtf(ss + 1e-12f);
        if (halfid == 0) {
            float irr = 1.f / rr;
            short8 ov;
#pragma unroll
            for (int j = 0; j < 8; j++) ov[j] = (short)f2bf(o[j] * irr);
            ((short8*)hnout)[(long)node * 32 + l32] = ov;
            if (l32 == 0) rout[node] = rr;
        }
    } else {
        if (halfid == 0) {
            float4 lo = make_float4(o[0], o[1], o[2], o[3]);
            float4 hi = make_float4(o[4], o[5], o[6], o[7]);
            ((float4*)hout)[(long)node * 64 + l32 * 2] = lo;
            ((float4*)hout)[(long)node * 64 + l32 * 2 + 1] = hi;
        }
    }
}

// ---------------- launch ----------------

extern "C" void kernel_launch(void* const* d_in, const int* in_sizes, int n_in,
                              void* d_out, int out_size, void* d_ws, size_t ws_size,
                              hipStream_t stream) {
    const float* x  = (const float*)d_in[0];
    const int* esrc = (const int*)d_in[1];
    const int* edst = (const int*)d_in[2];
    const float* W1 = (const float*)d_in[3];
    const float* b1 = (const float*)d_in[4];
    const float* W2 = (const float*)d_in[5];
    const float* b2 = (const float*)d_in[6];
    float* out = (float*)d_out;

    char* ws = (char*)d_ws;
    float*          h0     = (float*)(ws);                          // 20,480,000 B
    unsigned short* hnA    = (unsigned short*)(ws + 20480000);      // 10,240,000 B
    unsigned short* hnB    = (unsigned short*)(ws + 30720000);      // 10,240,000 B
    float*          rA     = (float*)(ws + 40960000);               // 80,000 B
    float*          rB     = (float*)(ws + 41040000);               // 80,000 B
    int*            indptr = (int*)  (ws + 41120000);               // 80,004 B (pad)
    int*            cnt    = (int*)  (ws + 41200256);               // 80,000 B
    int*            ssrc   = (int*)  (ws + 41280256);               // 2,640,000 B

    zero_cnt_kernel<<<(N_NODES + 255) / 256, 256, 0, stream>>>(cnt);
    count_kernel<<<(E_TOT + 255) / 256, 256, 0, stream>>>(edst, cnt);
    scan_kernel<<<1, 1024, 0, stream>>>(cnt, indptr);
    scatter_kernel<<<(E_TOT + 255) / 256, 256, 0, stream>>>(esrc, edst, indptr, cnt, ssrc);

    dim3 g1((N_NODES + 63) / 64, HIDDEN / 64);
    gemm_bias_act<<<g1, 256, 0, stream>>>(x, W1, b1, h0, N_NODES, HIDDEN, IN_DIM, 1);

    normalize0_kernel<<<N_NODES, 256, 0, stream>>>(h0, hnA, rA);

    int nblk = (N_NODES + 3) / 4;
    // L0: A -> B, L1: B -> A, L2: A -> B, L3: B -> h0 (fp32)
    agnn_kernel<<<nblk, 256, 0, stream>>>(hnA, rA, indptr, ssrc, hnB, rB, h0, 1);
    agnn_kernel<<<nblk, 256, 0, stream>>>(hnB, rB, indptr, ssrc, hnA, rA, h0, 1);
    agnn_kernel<<<nblk, 256, 0, stream>>>(hnA, rA, indptr, ssrc, hnB, rB, h0, 1);
    agnn_kernel<<<nblk, 256, 0, stream>>>(hnB, rB, indptr, ssrc, hnA, rA, h0, 0);

    dim3 g2((N_NODES + 63) / 64, OUT_DIM / 64);
    gemm_bias_act<<<g2, 256, 0, stream>>>(h0, W2, b2, out, N_NODES, OUT_DIM, HIDDEN, 0);
}

// Round 3
// 349.249 us; speedup vs baseline: 1.8739x; 1.0447x over previous
//
#include <hip/hip_runtime.h>

#define N_NODES 20000
#define N_EDGES 640000
#define E_TOT   (N_EDGES + N_NODES)   /* 660000: edges + self loops */
#define IN_DIM  128
#define HIDDEN  256
#define OUT_DIM 64
#define LOG2E 1.4426950408889634f

typedef __attribute__((ext_vector_type(2))) float f32x2;

__device__ __forceinline__ unsigned short f2bf(float f) {
    union { float f; unsigned int i; } x; x.f = f;
    unsigned int u = x.i;
    return (unsigned short)((u + 0x7fffu + ((u >> 16) & 1u)) >> 16);  // RTNE
}
__device__ __forceinline__ f32x2 up2(unsigned int p) {   // 2 packed bf16 -> 2 fp32
    f32x2 r;
    r.x = __uint_as_float(p << 16);
    r.y = __uint_as_float(p & 0xffff0000u);
    return r;
}
__device__ __forceinline__ unsigned int pk2(float a, float b) {
    return (unsigned int)f2bf(a) | ((unsigned int)f2bf(b) << 16);
}

// ---------------- CSR build (by dst) ----------------

__global__ void zero_cnt_kernel(int* __restrict__ cnt) {
    int i = blockIdx.x * blockDim.x + threadIdx.x;
    if (i < N_NODES) cnt[i] = 0;
}

__global__ void count_kernel(const int* __restrict__ edge_dst, int* __restrict__ cnt) {
    int i = blockIdx.x * blockDim.x + threadIdx.x;
    if (i >= E_TOT) return;
    int d = (i < N_EDGES) ? edge_dst[i] : (i - N_EDGES);   // implicit self-loop tail
    atomicAdd(&cnt[d], 1);
}

__global__ __launch_bounds__(1024) void scan_kernel(int* __restrict__ cnt, int* __restrict__ indptr) {
    const int T = 1024;
    const int C = (N_NODES + T - 1) / T;   // 20 per thread
    __shared__ int sums[T];
    int t = threadIdx.x;
    int base = t * C;
    int local[C];
    int s = 0;
#pragma unroll
    for (int i = 0; i < C; i++) {
        int idx = base + i;
        int v = (idx < N_NODES) ? cnt[idx] : 0;
        local[i] = s;
        s += v;
    }
    sums[t] = s;
    __syncthreads();
    for (int off = 1; off < T; off <<= 1) {
        int v = (t >= off) ? sums[t - off] : 0;
        __syncthreads();
        sums[t] += v;
        __syncthreads();
    }
    int prefix = (t == 0) ? 0 : sums[t - 1];
#pragma unroll
    for (int i = 0; i < C; i++) {
        int idx = base + i;
        if (idx < N_NODES) {
            indptr[idx] = prefix + local[i];
            cnt[idx] = 0;                   // cursor for scatter
        }
    }
    if (t == T - 1) indptr[N_NODES] = prefix + s;   // == E_TOT
}

__global__ void scatter_kernel(const int* __restrict__ edge_src, const int* __restrict__ edge_dst,
                               const int* __restrict__ indptr, int* __restrict__ cnt,
                               int* __restrict__ ssrc) {
    int i = blockIdx.x * blockDim.x + threadIdx.x;
    if (i >= E_TOT) return;
    int d, s;
    if (i < N_EDGES) { d = edge_dst[i]; s = edge_src[i]; }
    else             { d = i - N_EDGES; s = d; }
    int pos = indptr[d] + atomicAdd(&cnt[d], 1);
    ssrc[pos] = s;
}

// ---------------- fp32 tiled GEMM + bias + optional relu ----------------

__global__ __launch_bounds__(256) void gemm_bias_act(const float* __restrict__ A,
                                                     const float* __restrict__ B,
                                                     const float* __restrict__ bias,
                                                     float* __restrict__ C,
                                                     int M, int Nn, int K, int relu) {
    __shared__ float As[16][65];
    __shared__ float Bs[16][65];
    int tid = threadIdx.x;
    int tx = tid & 15, ty = tid >> 4;
    int row0 = blockIdx.x * 64, col0 = blockIdx.y * 64;
    float acc[4][4] = {};
    for (int k0 = 0; k0 < K; k0 += 16) {
        {
            int r_ = tid >> 2;
            int kq = (tid & 3) * 4;
            int gr = row0 + r_;
            float4 a4 = make_float4(0.f, 0.f, 0.f, 0.f);
            if (gr < M) a4 = *(const float4*)&A[(long)gr * K + k0 + kq];
            As[kq + 0][r_] = a4.x; As[kq + 1][r_] = a4.y;
            As[kq + 2][r_] = a4.z; As[kq + 3][r_] = a4.w;
        }
        {
            int kr = tid >> 4;
            int cq = (tid & 15) * 4;
            float4 b4 = *(const float4*)&B[(long)(k0 + kr) * Nn + col0 + cq];
            Bs[kr][cq + 0] = b4.x; Bs[kr][cq + 1] = b4.y;
            Bs[kr][cq + 2] = b4.z; Bs[kr][cq + 3] = b4.w;
        }
        __syncthreads();
#pragma unroll
        for (int kk = 0; kk < 16; kk++) {
            float a[4], b[4];
#pragma unroll
            for (int i = 0; i < 4; i++) a[i] = As[kk][ty * 4 + i];
#pragma unroll
            for (int j = 0; j < 4; j++) b[j] = Bs[kk][tx * 4 + j];
#pragma unroll
            for (int i = 0; i < 4; i++)
#pragma unroll
                for (int j = 0; j < 4; j++) acc[i][j] += a[i] * b[j];
        }
        __syncthreads();
    }
#pragma unroll
    for (int i = 0; i < 4; i++) {
        int gr = row0 + ty * 4 + i;
        if (gr >= M) continue;
#pragma unroll
        for (int j = 0; j < 4; j++) {
            int gc = col0 + tx * 4 + j;
            float v = acc[i][j] + bias[gc];
            if (relu) v = fmaxf(v, 0.f);
            C[(long)gr * Nn + gc] = v;
        }
    }
}

// ---------------- initial normalize: fp32 h -> bf16 hn + fp32 r ----------------

__global__ __launch_bounds__(256) void normalize0_kernel(const float* __restrict__ h,
                                                         unsigned short* __restrict__ hnb,
                                                         float* __restrict__ r) {
    int i = blockIdx.x;
    int c = threadIdx.x;
    float v = h[(long)i * HIDDEN + c];
    float ss = v * v;
#pragma unroll
    for (int off = 32; off; off >>= 1) ss += __shfl_xor(ss, off);
    __shared__ float wsum[4];
    int wid = c >> 6, lane = c & 63;
    if (lane == 0) wsum[wid] = ss;
    __syncthreads();
    float tot = wsum[0] + wsum[1] + wsum[2] + wsum[3];
    float rr = sqrtf(tot + 1e-12f);
    hnb[(long)i * HIDDEN + c] = f2bf(v / rr);
    if (c == 0) r[i] = rr;
}

// ---------------- fused AGNN layer ----------------
// One node per 16-lane group (4 nodes/wave, 16 ch/lane as f32x2[8]).
// Softmax without max-subtraction: logits are cosines in [-1,1], exp() range
// [0.37, 2.7] -- no overflow possible; ratio identical to reference.
// hd pre-scaled by log2e so weight = exp2(dot).

__global__ __launch_bounds__(256) void agnn_kernel(const unsigned short* __restrict__ hnb,
                                                   const float* __restrict__ rin,
                                                   const int* __restrict__ indptr,
                                                   const int* __restrict__ ssrc,
                                                   unsigned short* __restrict__ hnout,
                                                   float* __restrict__ rout,
                                                   float* __restrict__ hout,
                                                   int write_hn) {
    int lane = threadIdx.x & 63;
    int wid  = threadIdx.x >> 6;
    int gid  = lane >> 4;          // group within wave (0..3)
    int gl   = lane & 15;          // lane within group
    int node = blockIdx.x * 16 + wid * 4 + gid;   // grid is exact: 1250*16 = 20000

    const uint4* tab4 = (const uint4*)hnb;        // one uint4 = 8 bf16
    long nb = (long)node * 32 + gl * 2;           // row stride = 32 uint4
    uint4 ha = tab4[nb], hb = tab4[nb + 1];
    f32x2 hd2[8];
    {
        f32x2 t;
        t = up2(ha.x); hd2[0] = t * LOG2E;
        t = up2(ha.y); hd2[1] = t * LOG2E;
        t = up2(ha.z); hd2[2] = t * LOG2E;
        t = up2(ha.w); hd2[3] = t * LOG2E;
        t = up2(hb.x); hd2[4] = t * LOG2E;
        t = up2(hb.y); hd2[5] = t * LOG2E;
        t = up2(hb.z); hd2[6] = t * LOG2E;
        t = up2(hb.w); hd2[7] = t * LOG2E;
    }

    int beg = indptr[node], end = indptr[node + 1];
    int n = end - beg;                 // >= 1 (self loop)
    int last = end - 1;

    f32x2 acc[8];
#pragma unroll
    for (int p = 0; p < 8; p++) acc[p] = (f32x2)0.f;
    float z = 0.f;

    int s = ssrc[beg];
    long sb = (long)s * 32 + gl * 2;
    uint4 va = tab4[sb], vb = tab4[sb + 1];
    float rs = rin[s];

    for (int i = 0; i < n; i++) {
        uint4 ca = va, cb = vb;
        float cr = rs;
        {   // branchless prefetch (clamped; last iter re-reads cached line)
            int nx = beg + i + 1;
            nx = (nx > last) ? last : nx;
            int s2 = ssrc[nx];
            long b2 = (long)s2 * 32 + gl * 2;
            va = tab4[b2]; vb = tab4[b2 + 1];
            rs = rin[s2];
        }
        f32x2 cf[8];
        cf[0] = up2(ca.x); cf[1] = up2(ca.y); cf[2] = up2(ca.z); cf[3] = up2(ca.w);
        cf[4] = up2(cb.x); cf[5] = up2(cb.y); cf[6] = up2(cb.z); cf[7] = up2(cb.w);
        // two parallel pk-fma chains for the dot
        f32x2 d2a = cf[0] * hd2[0];
        f32x2 d2b = cf[1] * hd2[1];
        d2a += cf[2] * hd2[2];  d2b += cf[3] * hd2[3];
        d2a += cf[4] * hd2[4];  d2b += cf[5] * hd2[5];
        d2a += cf[6] * hd2[6];  d2b += cf[7] * hd2[7];
        f32x2 d2 = d2a + d2b;
        float d = d2.x + d2.y;
        d += __shfl_xor(d, 1, 16);
        d += __shfl_xor(d, 2, 16);
        d += __shfl_xor(d, 4, 16);
        d += __shfl_xor(d, 8, 16);
        float w = exp2f(d);        // d = cos * log2e, |d| <= ~1.45
        z += w;
        float wr = w * cr;
#pragma unroll
        for (int p = 0; p < 8; p++) acc[p] += cf[p] * wr;
    }

    float inv = 1.f / z;
    f32x2 o[8];
#pragma unroll
    for (int p = 0; p < 8; p++) {
        f32x2 t = acc[p] * inv;
        t.x = fmaxf(t.x, 0.f);
        t.y = fmaxf(t.y, 0.f);
        o[p] = t;
    }

    if (write_hn) {
        float ss = 0.f;
#pragma unroll
        for (int p = 0; p < 8; p++) ss += o[p].x * o[p].x + o[p].y * o[p].y;
        ss += __shfl_xor(ss, 1, 16);
        ss += __shfl_xor(ss, 2, 16);
        ss += __shfl_xor(ss, 4, 16);
        ss += __shfl_xor(ss, 8, 16);
        float rr = sqrtf(ss + 1e-12f);
        float ir = 1.f / rr;
        uint4 oa, ob;
        oa.x = pk2(o[0].x * ir, o[0].y * ir);
        oa.y = pk2(o[1].x * ir, o[1].y * ir);
        oa.z = pk2(o[2].x * ir, o[2].y * ir);
        oa.w = pk2(o[3].x * ir, o[3].y * ir);
        ob.x = pk2(o[4].x * ir, o[4].y * ir);
        ob.y = pk2(o[5].x * ir, o[5].y * ir);
        ob.z = pk2(o[6].x * ir, o[6].y * ir);
        ob.w = pk2(o[7].x * ir, o[7].y * ir);
        uint4* outt = (uint4*)hnout;
        outt[nb] = oa;
        outt[nb + 1] = ob;
        if (gl == 0) rout[node] = rr;
    } else {
        float4* ho = (float4*)(hout + (long)node * HIDDEN + gl * 16);
        ho[0] = make_float4(o[0].x, o[0].y, o[1].x, o[1].y);
        ho[1] = make_float4(o[2].x, o[2].y, o[3].x, o[3].y);
        ho[2] = make_float4(o[4].x, o[4].y, o[5].x, o[5].y);
        ho[3] = make_float4(o[6].x, o[6].y, o[7].x, o[7].y);
    }
}

// ---------------- launch ----------------

extern "C" void kernel_launch(void* const* d_in, const int* in_sizes, int n_in,
                              void* d_out, int out_size, void* d_ws, size_t ws_size,
                              hipStream_t stream) {
    const float* x  = (const float*)d_in[0];
    const int* esrc = (const int*)d_in[1];
    const int* edst = (const int*)d_in[2];
    const float* W1 = (const float*)d_in[3];
    const float* b1 = (const float*)d_in[4];
    const float* W2 = (const float*)d_in[5];
    const float* b2 = (const float*)d_in[6];
    float* out = (float*)d_out;

    char* ws = (char*)d_ws;
    float*          h0     = (float*)(ws);                          // 20,480,000 B
    unsigned short* hnA    = (unsigned short*)(ws + 20480000);      // 10,240,000 B
    unsigned short* hnB    = (unsigned short*)(ws + 30720000);      // 10,240,000 B
    float*          rA     = (float*)(ws + 40960000);               // 80,000 B
    float*          rB     = (float*)(ws + 41040000);               // 80,000 B
    int*            indptr = (int*)  (ws + 41120000);               // 80,004 B (pad)
    int*            cnt    = (int*)  (ws + 41200256);               // 80,000 B
    int*            ssrc   = (int*)  (ws + 41280256);               // 2,640,000 B

    zero_cnt_kernel<<<(N_NODES + 255) / 256, 256, 0, stream>>>(cnt);
    count_kernel<<<(E_TOT + 255) / 256, 256, 0, stream>>>(edst, cnt);
    scan_kernel<<<1, 1024, 0, stream>>>(cnt, indptr);
    scatter_kernel<<<(E_TOT + 255) / 256, 256, 0, stream>>>(esrc, edst, indptr, cnt, ssrc);

    dim3 g1((N_NODES + 63) / 64, HIDDEN / 64);
    gemm_bias_act<<<g1, 256, 0, stream>>>(x, W1, b1, h0, N_NODES, HIDDEN, IN_DIM, 1);

    normalize0_kernel<<<N_NODES, 256, 0, stream>>>(h0, hnA, rA);

    int nblk = N_NODES / 16;   // 1250, exact
    // L0: A -> B, L1: B -> A, L2: A -> B, L3: B -> h0 (fp32)
    agnn_kernel<<<nblk, 256, 0, stream>>>(hnA, rA, indptr, ssrc, hnB, rB, h0, 1);
    agnn_kernel<<<nblk, 256, 0, stream>>>(hnB, rB, indptr, ssrc, hnA, rA, h0, 1);
    agnn_kernel<<<nblk, 256, 0, stream>>>(hnA, rA, indptr, ssrc, hnB, rB, h0, 1);
    agnn_kernel<<<nblk, 256, 0, stream>>>(hnB, rB, indptr, ssrc, hnA, rA, h0, 0);

    dim3 g2((N_NODES + 63) / 64, OUT_DIM / 64);
    gemm_bias_act<<<g2, 256, 0, stream>>>(h0, W2, b2, out, N_NODES, OUT_DIM, HIDDEN, 0);
}